// Round 1
// baseline (560.923 us; speedup 1.0000x reference)
//
#include <hip/hip_runtime.h>

// YOLO layer decode: B=64, A=3, NC=80, H=W=80.
// Input  [B, A*(5+NC), H, W] f32, anchors [3,2] f32, nms_tresh [1] f32.
// Output: boxes [B,A,H,W,7] f32 then keep [B,A,H,W] (0/1 as f32), flat-concat.

#define SIG(x) (1.0f / (1.0f + __expf(-(x))))

// online max/argmax/sum-exp update (branchless, first-max-wins via strict >)
#define UPD(m, s, id, x, fc)                         \
    {                                                \
        float _nm = fmaxf((m), (x));                 \
        (s) = (s) * __expf((m) - _nm) + __expf((x) - _nm); \
        (id) = ((x) > (m)) ? (fc) : (id);            \
        (m) = _nm;                                   \
    }

__global__ __launch_bounds__(256) void yolo_kernel(
    const float* __restrict__ in,
    const float* __restrict__ anchors,
    const float* __restrict__ nms,
    float* __restrict__ out)
{
    constexpr int HWq = 6400 / 4;           // float4 stride per channel
    constexpr long BOXES = 64L * 3 * 80 * 80 * 7;  // 8601600
    constexpr float INV_W = 1.0f / 80.0f;
    constexpr float INV_H = 1.0f / 80.0f;

    int t = blockIdx.x * blockDim.x + threadIdx.x;   // 0 .. 307199
    if (t >= 307200) return;
    int pos = t << 2;                // element index in [B,A,H,W] space
    int hw  = pos % 6400;            // h*80 + w
    int ba  = pos / 6400;            // b*3 + a
    int a   = ba % 3;
    int w0  = hw % 80;
    int h   = hw / 80;

    const float4* p = reinterpret_cast<const float4*>(in)
                      + (long)ba * 85 * HWq + (hw >> 2);

    float4 v0 = p[0 * HWq];   // tx
    float4 v1 = p[1 * HWq];   // ty
    float4 v2 = p[2 * HWq];   // tw
    float4 v3 = p[3 * HWq];   // th
    float4 v4 = p[4 * HWq];   // obj

    // online softmax over 80 classes (single HBM pass)
    float m0 = -1e30f, m1 = -1e30f, m2 = -1e30f, m3 = -1e30f;
    float s0 = 0.0f,  s1 = 0.0f,  s2 = 0.0f,  s3 = 0.0f;
    float i0 = 0.0f,  i1 = 0.0f,  i2 = 0.0f,  i3 = 0.0f;

    #pragma unroll 4
    for (int c = 0; c < 80; ++c) {
        float4 x = p[(5 + c) * HWq];
        float fc = (float)c;
        UPD(m0, s0, i0, x.x, fc);
        UPD(m1, s1, i1, x.y, fc);
        UPD(m2, s2, i2, x.z, fc);
        UPD(m3, s3, i3, x.w, fc);
    }

    float an0 = anchors[2 * a] * INV_W;
    float an1 = anchors[2 * a + 1] * INV_H;
    float th  = nms[0];
    float fh  = (float)h;

    #define EPI(j, VX)                                              \
        float X##j  = (SIG(v0.VX) + (float)(w0 + j)) * INV_W;       \
        float Y##j  = (SIG(v1.VX) + fh) * INV_H;                    \
        float Wb##j = __expf(v2.VX) * an0;                          \
        float Hb##j = __expf(v3.VX) * an1;                          \
        float D##j  = SIG(v4.VX);                                   \
        float Cf##j = 1.0f / s##j;                                  \
        float K##j  = (D##j > th) ? 1.0f : 0.0f;

    EPI(0, x)
    EPI(1, y)
    EPI(2, z)
    EPI(3, w)

    // boxes: 28 consecutive floats per thread -> 7 aligned float4 stores
    float4* q = reinterpret_cast<float4*>(out + (long)pos * 7);
    q[0] = make_float4(X0,  Y0,  Wb0, Hb0);
    q[1] = make_float4(D0,  Cf0, i0,  X1);
    q[2] = make_float4(Y1,  Wb1, Hb1, D1);
    q[3] = make_float4(Cf1, i1,  X2,  Y2);
    q[4] = make_float4(Wb2, Hb2, D2,  Cf2);
    q[5] = make_float4(i2,  X3,  Y3,  Wb3);
    q[6] = make_float4(Hb3, D3,  Cf3, i3);

    // keep mask: 4 consecutive floats
    *reinterpret_cast<float4*>(out + BOXES + pos) = make_float4(K0, K1, K2, K3);
}

extern "C" void kernel_launch(void* const* d_in, const int* in_sizes, int n_in,
                              void* d_out, int out_size, void* d_ws, size_t ws_size,
                              hipStream_t stream)
{
    const float* in      = (const float*)d_in[0];
    const float* anchors = (const float*)d_in[1];
    const float* nms     = (const float*)d_in[2];
    float* out           = (float*)d_out;

    // 307200 threads, one per 4 consecutive (h,w) positions
    dim3 grid(1200), block(256);
    hipLaunchKernelGGL(yolo_kernel, grid, block, 0, stream, in, anchors, nms, out);
}